// Round 12
// baseline (161.290 us; speedup 1.0000x reference)
//
#include <hip/hip_runtime.h>
#include <hip/hip_bf16.h>
#include <stdint.h>

#define K_DIM 1024
#define N_DIM 1024
#define NT    32     // K-tiles of BK=32

typedef __attribute__((ext_vector_type(8))) short  short8;
typedef __attribute__((ext_vector_type(4))) float  f32x4;
typedef __attribute__((ext_vector_type(4))) unsigned int u32x4;

__device__ __forceinline__ ushort f2bf(float f) {
  union { float f; uint32_t u; } v; v.f = f;
  uint32_t r = v.u + 0x7FFFu + ((v.u >> 16) & 1u);
  return (ushort)(r >> 16);
}
__device__ __forceinline__ uint32_t pack_bf2(float a, float b) {
  __hip_bfloat162 h = __float22bfloat162_rn(make_float2(a, b));
  union { __hip_bfloat162 h; uint32_t u; } c; c.h = h;
  return c.u;
}

// ---------------- kernel 1: materialize Toeplitz matrix as bf16 -------------
__global__ __launch_bounds__(256) void build_T_kernel(
    const float* __restrict__ fr, const float* __restrict__ fc,
    ushort* __restrict__ T) {
  int idx = blockIdx.x * 256 + threadIdx.x;
  int o  = idx >> 7;
  int i0 = (idx & 127) << 3;
  short8 v;
#pragma unroll
  for (int j = 0; j < 8; ++j) {
    int d = o - (i0 + j);
    float f = (d >= 0) ? fc[d] : fr[-d];
    v[j] = (short)f2bf(f);
  }
  *reinterpret_cast<short8*>(T + (size_t)idx * 8) = v;
}

// ---- kernel 2: BM=64 x BN=1024; A resident in LDS; barrier-free K-loop -----
// 8 waves; wave wv owns cols wv*128..+128 (8 nf). A (64x1024 bf16, swizzled)
// converted from fp32 in phase 0. B fragments: global->reg, 1-tile ping-pong.
__global__ __launch_bounds__(512, 2) void gemm_fusedA(
    const float* __restrict__ X, const ushort* __restrict__ T,
    const float* __restrict__ bias, float* __restrict__ Out) {
  __shared__ alignas(16) char smem[131072];   // A: 64 rows x 2048 B

  const int tid  = threadIdx.x;
  const int lane = tid & 63;
  const int wv   = tid >> 6;                  // 0..7
  const int cc   = lane & 15, kg = lane >> 4; // frag col / k-group
  const int m0   = blockIdx.x * 64;
  const int n0   = wv * 128;

  // ---- phase 0: convert this block's x panel fp32 -> bf16 into LDS ----
  {
    const int r  = tid >> 3;                  // 0..63
    const int kc = tid & 7;                   // 128-float chunk
    const float* xp = X + (size_t)(m0 + r) * K_DIM + kc * 128;
    const int swz = (r & 7) << 4;
#pragma unroll
    for (int i = 0; i < 16; ++i) {
      f32x4 a = *reinterpret_cast<const f32x4*>(xp + i * 8);
      f32x4 b = *reinterpret_cast<const f32x4*>(xp + i * 8 + 4);
      u32x4 p;
      p.x = pack_bf2(a.x, a.y); p.y = pack_bf2(a.z, a.w);
      p.z = pack_bf2(b.x, b.y); p.w = pack_bf2(b.z, b.w);
      *reinterpret_cast<u32x4*>(
          smem + r * 2048 + ((kc * 256 + i * 16) ^ swz)) = p;
    }
  }
  __syncthreads();                            // the ONLY barrier

  // ---- K-loop: B global->reg ping-pong; A from LDS; no barriers ----
  const ushort* bp = T + (size_t)(n0 + cc) * K_DIM + kg * 8;
  const int aswz = (cc & 7) << 4;

  short8 bA[8], bB[8], afr[4];
  f32x4  acc[4][8];
#pragma unroll
  for (int mf = 0; mf < 4; ++mf)
#pragma unroll
    for (int nf = 0; nf < 8; ++nf)
      acc[mf][nf] = (f32x4){0.f, 0.f, 0.f, 0.f};

#define LDB(arr, t)                                                         \
  { _Pragma("unroll")                                                       \
    for (int nf = 0; nf < 8; ++nf)                                          \
      arr[nf] = *reinterpret_cast<const short8*>(                           \
          bp + (size_t)nf * 16 * K_DIM + (t) * 32); }

#define READA(t)                                                            \
  { _Pragma("unroll")                                                       \
    for (int mf = 0; mf < 4; ++mf)                                          \
      afr[mf] = *reinterpret_cast<const short8*>(                           \
          smem + mf * 32768 + cc * 2048 + (((t) * 64 + kg * 16) ^ aswz)); }

#define MFMAS(Bb)                                                           \
  { __builtin_amdgcn_s_setprio(1);                                         \
    _Pragma("unroll")                                                       \
    for (int mf = 0; mf < 4; ++mf)                                          \
      _Pragma("unroll")                                                     \
      for (int nf = 0; nf < 8; ++nf)                                        \
        acc[mf][nf] = __builtin_amdgcn_mfma_f32_16x16x32_bf16(              \
            afr[mf], Bb[nf], acc[mf][nf], 0, 0, 0);                         \
    __builtin_amdgcn_s_setprio(0); }

  LDB(bA, 0);
#pragma unroll 1
  for (int t = 0; t < NT; t += 2) {
    LDB(bB, t + 1);                 // prefetch odd tile
    READA(t);
    MFMAS(bA);                      // compiler waits bA (counted vmcnt)
    if (t + 2 < NT) LDB(bA, t + 2); // prefetch next even tile
    READA(t + 1);
    MFMAS(bB);
  }

  // ---- epilogue: bias + fp32 store ----
#pragma unroll
  for (int nf = 0; nf < 8; ++nf) {
    const int col = n0 + nf * 16 + cc;
    const float bv = bias[col];
#pragma unroll
    for (int mf = 0; mf < 4; ++mf) {
      const int row0 = m0 + mf * 16 + kg * 4;
      float* op = Out + (size_t)row0 * N_DIM + col;
#pragma unroll
      for (int j = 0; j < 4; ++j)
        op[(size_t)j * N_DIM] = acc[mf][nf][j] + bv;
    }
  }
#undef LDB
#undef READA
#undef MFMAS
}

// ---------------- fallback (ws too small): naive fp32 ----------------------
__global__ __launch_bounds__(256) void toeplitz_naive(
    const float* __restrict__ x, const float* __restrict__ fr,
    const float* __restrict__ fc, const float* __restrict__ bias,
    float* __restrict__ out) {
  __shared__ float sx[1024], sfr[1024], sfc[1024];
  const int m = blockIdx.x;
  for (int i = threadIdx.x; i < 1024; i += 256) {
    sx[i]  = x[(size_t)m * 1024 + i];
    sfr[i] = fr[i];
    sfc[i] = fc[i];
  }
  __syncthreads();
  for (int q = 0; q < 4; ++q) {
    const int o = threadIdx.x + q * 256;
    float acc = bias[o];
    for (int i = 0; i <= o; ++i)       acc += sx[i] * sfc[o - i];
    for (int i = o + 1; i < 1024; ++i) acc += sx[i] * sfr[i - o];
    out[(size_t)m * 1024 + o] = acc;
  }
}

extern "C" void kernel_launch(void* const* d_in, const int* in_sizes, int n_in,
                              void* d_out, int out_size, void* d_ws, size_t ws_size,
                              hipStream_t stream) {
  const float* x    = (const float*)d_in[0];
  const float* fr   = (const float*)d_in[1];
  const float* fc   = (const float*)d_in[2];
  const float* bias = (const float*)d_in[3];
  float* out = (float*)d_out;

  if (ws_size >= (size_t)2 * 1024 * 1024) {
    ushort* T = (ushort*)d_ws;
    build_T_kernel<<<dim3(512), dim3(256), 0, stream>>>(fr, fc, T);
    gemm_fusedA<<<dim3(512), dim3(512), 0, stream>>>(x, T, bias, out);
  } else {
    toeplitz_naive<<<dim3(32768), dim3(256), 0, stream>>>(x, fr, fc, bias, out);
  }
}

// Round 13
// 127.739 us; speedup vs baseline: 1.2626x; 1.2626x over previous
//
#include <hip/hip_runtime.h>
#include <hip/hip_bf16.h>
#include <stdint.h>

#define K_DIM 1024
#define N_DIM 1024

typedef __attribute__((ext_vector_type(8))) short  short8;
typedef __attribute__((ext_vector_type(4))) float  f32x4;
typedef __attribute__((ext_vector_type(4))) unsigned int u32x4;

__device__ __forceinline__ ushort f2bf(float f) {
  union { float f; uint32_t u; } v; v.f = f;
  uint32_t r = v.u + 0x7FFFu + ((v.u >> 16) & 1u);
  return (ushort)(r >> 16);
}
__device__ __forceinline__ uint32_t pack_bf2(float a, float b) {
  __hip_bfloat162 h = __float22bfloat162_rn(make_float2(a, b));
  union { __hip_bfloat162 h; uint32_t u; } c; c.h = h;
  return c.u;
}

// ---------------- kernel 1: materialize Toeplitz matrix as bf16 -------------
__global__ __launch_bounds__(256) void build_T_kernel(
    const float* __restrict__ fr, const float* __restrict__ fc,
    ushort* __restrict__ T) {
  int idx = blockIdx.x * 256 + threadIdx.x;
  int o  = idx >> 7;
  int i0 = (idx & 127) << 3;
  short8 v;
#pragma unroll
  for (int j = 0; j < 8; ++j) {
    int d = o - (i0 + j);
    float f = (d >= 0) ? fc[d] : fr[-d];
    v[j] = (short)f2bf(f);
  }
  *reinterpret_cast<short8*>(T + (size_t)idx * 8) = v;
}

// ---- kernel 2: 128x256 monolithic GEMM with in-pipeline fp32->bf16 stage ---
// LDS map: f32A [128r][256B] @0 (32K, single); bf16A @32768+sel*16384 (16K x2);
//          B @65536+sel*32768 (32K x2). Total 128 KiB.
__global__ __launch_bounds__(512, 2) void gemm_mono(
    const float* __restrict__ X, const ushort* __restrict__ T,
    const float* __restrict__ bias, float* __restrict__ Out) {
  __shared__ alignas(16) char smem[131072];

  const int tid  = threadIdx.x;
  const int lane = tid & 63;
  const int wv   = tid >> 6;
  const int wm   = wv >> 2, wn = wv & 3;      // 2x4 wave grid, 64x64 tiles
  const int cc   = lane & 15, kg = lane >> 4;

  // XCD swizzle: 1024 blocks = 8 xcd * 128; 4 consecutive share an m-panel.
  const int u  = (blockIdx.x & 7) * 128 + (blockIdx.x >> 3);
  const int m0 = (u >> 2) * 128;
  const int n0 = (u & 3) * 256;

  // A fp32 DMA: linear dest, granule-16B pre-swizzled source (r&15 XOR).
  const float* aSrcF = X + (size_t)(m0 + (tid >> 4)) * K_DIM
                         + ((tid & 15) ^ ((tid >> 4) & 15)) * 4;
  // B DMA: linear dest, (r&7)<<4 pre-swizzled source (R6-proven).
  const ushort* bSrc = T + (size_t)(n0 + (tid >> 3)) * K_DIM
                         + ((((tid & 7) * 16) ^ (((tid >> 3) & 7) << 4)) >> 1);

  // cvt stage: thread owns row r=tid>>2, k-quarter q=tid&3 (16 floats).
  const int cr_ = tid >> 2, cq = tid & 3;
  const int cR0 = cr_ * 256 + ((cq * 64 +  0) ^ ((cr_ & 15) << 4));
  const int cR1 = cr_ * 256 + ((cq * 64 + 16) ^ ((cr_ & 15) << 4));
  const int cR2 = cr_ * 256 + ((cq * 64 + 32) ^ ((cr_ & 15) << 4));
  const int cR3 = cr_ * 256 + ((cq * 64 + 48) ^ ((cr_ & 15) << 4));
  const int cW0 = cr_ * 128 + ((cq * 32)      ^ ((cr_ & 7) << 4));
  const int cW1 = cr_ * 128 + ((cq * 32 + 16) ^ ((cr_ & 7) << 4));

  // fragment read offsets
  const int kxA  = (cc & 7) << 4;
  const int aRow = (wm * 64 + cc) * 128;           // + mf*2048, base 32768+sel*16384
  const int bRow = (wn * 64 + cc) * 128;           // + nf*2048, base 65536+sel*32768

  f32x4  cr4[4];
  short8 afr[4], bfr[4];
  f32x4  acc[4][4] = {};

#define SB0() __builtin_amdgcn_sched_barrier(0)
#define BAR() __builtin_amdgcn_s_barrier()
#define LGKM0 asm volatile("s_waitcnt lgkmcnt(0)" ::: "memory")
#define GATE0 asm volatile("s_waitcnt vmcnt(0)" ::: "memory")
#define GATE4 asm volatile("s_waitcnt vmcnt(4)" ::: "memory")

#define DMA_A(t)                                                            \
  { _Pragma("unroll")                                                       \
    for (int i = 0; i < 4; ++i) {                                           \
      const float* src = aSrcF + (size_t)i * 32 * K_DIM + (t) * 64;         \
      char* dst = smem + i * 8192 + tid * 16;                               \
      __builtin_amdgcn_global_load_lds(                                     \
          (const __attribute__((address_space(1))) void*)src,               \
          (__attribute__((address_space(3))) void*)dst, 16, 0, 0);          \
    } }

#define DMA_B(t, sel)                                                       \
  { _Pragma("unroll")                                                       \
    for (int s = 0; s < 4; ++s) {                                           \
      const ushort* src = bSrc + (size_t)s * 64 * K_DIM + (t) * 64;         \
      char* dst = smem + 65536 + (sel) * 32768 + s * 8192 + tid * 16;       \
      __builtin_amdgcn_global_load_lds(                                     \
          (const __attribute__((address_space(1))) void*)src,               \
          (__attribute__((address_space(3))) void*)dst, 16, 0, 0);          \
    } }

#define CVTR()                                                              \
  { cr4[0] = *reinterpret_cast<const f32x4*>(smem + cR0);                   \
    cr4[1] = *reinterpret_cast<const f32x4*>(smem + cR1);                   \
    cr4[2] = *reinterpret_cast<const f32x4*>(smem + cR2);                   \
    cr4[3] = *reinterpret_cast<const f32x4*>(smem + cR3); }

#define CVTW(sel)                                                           \
  { u32x4 p0, p1;                                                           \
    p0.x = pack_bf2(cr4[0].x, cr4[0].y); p0.y = pack_bf2(cr4[0].z, cr4[0].w); \
    p0.z = pack_bf2(cr4[1].x, cr4[1].y); p0.w = pack_bf2(cr4[1].z, cr4[1].w); \
    p1.x = pack_bf2(cr4[2].x, cr4[2].y); p1.y = pack_bf2(cr4[2].z, cr4[2].w); \
    p1.z = pack_bf2(cr4[3].x, cr4[3].y); p1.w = pack_bf2(cr4[3].z, cr4[3].w); \
    *reinterpret_cast<u32x4*>(smem + 32768 + (sel) * 16384 + cW0) = p0;     \
    *reinterpret_cast<u32x4*>(smem + 32768 + (sel) * 16384 + cW1) = p1; }

#define RA(sel, kk)                                                         \
  { _Pragma("unroll")                                                       \
    for (int mf = 0; mf < 4; ++mf)                                          \
      afr[mf] = *reinterpret_cast<const short8*>(                           \
          smem + 32768 + (sel) * 16384 + aRow + mf * 2048 +                 \
          (((kk) * 64 + kg * 16) ^ kxA)); }

#define RB(sel, kk)                                                         \
  { _Pragma("unroll")                                                       \
    for (int nf = 0; nf < 4; ++nf)                                          \
      bfr[nf] = *reinterpret_cast<const short8*>(                           \
          smem + 65536 + (sel) * 32768 + bRow + nf * 2048 +                 \
          (((kk) * 64 + kg * 16) ^ kxA)); }

#define MM()                                                                \
  { __builtin_amdgcn_s_setprio(1);                                         \
    _Pragma("unroll")                                                       \
    for (int mf = 0; mf < 4; ++mf)                                          \
      _Pragma("unroll")                                                     \
      for (int nf = 0; nf < 4; ++nf)                                        \
        acc[mf][nf] = __builtin_amdgcn_mfma_f32_16x16x32_bf16(              \
            afr[mf], bfr[nf], acc[mf][nf], 0, 0, 0);                        \
    __builtin_amdgcn_s_setprio(0); }

  // ---- prologue ----
  DMA_A(0); SB0(); DMA_B(0, 0); SB0();
  GATE0; BAR();                 // f32(0) + B(0) landed
  CVTR();                       // read f32(0)
  LGKM0; BAR();                 // all waves done reading f32 buf
  DMA_A(1); SB0(); DMA_B(1, 1); SB0();
  CVTW(0);                      // bf16[0] = tile 0
  LGKM0;
  GATE4;                        // retire A(1) (keeps B(1) in flight)
  BAR();

#pragma unroll 1
  for (int t = 0; t < 16; ++t) {
    const int sel = t & 1;
    // ---- P1: cvt-read f32(t+1); frag reads kk0; DMA A(t+2); MFMA ----
    if (t < 15) CVTR();
    RA(sel, 0); RB(sel, 0);
    SB0(); BAR(); SB0();
    if (t < 14) { DMA_A(t + 2); SB0(); }
    MM();
    SB0(); BAR(); SB0();
    // ---- P2: cvt-write bf16(t+1); frag reads kk1; DMA B(t+2); MFMA ----
    if (t < 15) CVTW(sel ^ 1);
    RA(sel, 1); RB(sel, 1);
    LGKM0; BAR(); SB0();
    if (t < 14) { DMA_B(t + 2, sel); SB0(); }
    MM();
    GATE0;                      // A(t+2) ~1600cy old; B(t+2) L2-hot
    BAR();
  }

  // ---- epilogue: bias + fp32 store ----
#pragma unroll
  for (int nf = 0; nf < 4; ++nf) {
    const int col = n0 + wn * 64 + nf * 16 + cc;
    const float bv = bias[col];
#pragma unroll
    for (int mf = 0; mf < 4; ++mf) {
      const int row0 = m0 + wm * 64 + mf * 16 + kg * 4;
      float* op = Out + (size_t)row0 * N_DIM + col;
#pragma unroll
      for (int j = 0; j < 4; ++j)
        op[(size_t)j * N_DIM] = acc[mf][nf][j] + bv;
    }
  }
#undef DMA_A
#undef DMA_B
#undef CVTR
#undef CVTW
#undef RA
#undef RB
#undef MM
#undef SB0
#undef BAR
#undef LGKM0
#undef GATE0
#undef GATE4
}

// ---------------- fallback (ws too small): naive fp32 ----------------------
__global__ __launch_bounds__(256) void toeplitz_naive(
    const float* __restrict__ x, const float* __restrict__ fr,
    const float* __restrict__ fc, const float* __restrict__ bias,
    float* __restrict__ out) {
  __shared__ float sx[1024], sfr[1024], sfc[1024];
  const int m = blockIdx.x;
  for (int i = threadIdx.x; i < 1024; i += 256) {
    sx[i]  = x[(size_t)m * 1024 + i];
    sfr[i] = fr[i];
    sfc[i] = fc[i];
  }
  __syncthreads();
  for (int q = 0; q < 4; ++q) {
    const int o = threadIdx.x + q * 256;
    float acc = bias[o];
    for (int i = 0; i <= o; ++i)       acc += sx[i] * sfc[o - i];
    for (int i = o + 1; i < 1024; ++i) acc += sx[i] * sfr[i - o];
    out[(size_t)m * 1024 + o] = acc;
  }
}

extern "C" void kernel_launch(void* const* d_in, const int* in_sizes, int n_in,
                              void* d_out, int out_size, void* d_ws, size_t ws_size,
                              hipStream_t stream) {
  const float* x    = (const float*)d_in[0];
  const float* fr   = (const float*)d_in[1];
  const float* fc   = (const float*)d_in[2];
  const float* bias = (const float*)d_in[3];
  float* out = (float*)d_out;

  if (ws_size >= (size_t)2 * 1024 * 1024) {
    ushort* T = (ushort*)d_ws;
    build_T_kernel<<<dim3(512), dim3(256), 0, stream>>>(fr, fc, T);
    gemm_mono<<<dim3(1024), dim3(512), 0, stream>>>(x, T, bias, out);
  } else {
    toeplitz_naive<<<dim3(32768), dim3(256), 0, stream>>>(x, fr, fc, bias, out);
  }
}